// Round 13
// baseline (91.663 us; speedup 1.0000x reference)
//
#include <hip/hip_runtime.h>
#include <math.h>

#define WS 21
#define KWIN 43            // 2*WS+1
#define H 128
#define W 128
#define B 2
#define C 3
#define HW (H * W)
#define CHW (C * H * W)
#define NPIX (B * H * W)   // 32768
#define SIGMA_SPACE (1.0f / 98.0f)
#define NSPLIT 16          // r13: 8 -> 16 (8192 waves, 8 blocks/CU) for latency hiding
#define SQ_THR_FP16 0.17f  // fp16-screen threshold (validated r7-r12, absmax ~0)
#define NEG_SC_LOG2E 72.1347520445f   // 50*log2(e)
#define SG 17.509290f      // sum_{k=-21..21} exp(-k^2/98)
#define WSLOTS 108         // wave-private LDS slice (106 used, uint2 units)

typedef _Float16 h2_t __attribute__((ext_vector_type(2)));

// Compiler-only fence: wave-private LDS relies on HW per-wave DS ordering; this
// stops compiler reordering of lane-local LDS ops whose cross-lane aliasing it
// cannot see (r10 bug -> r11 fix, validated absmax 1.0 -> 0.0).
#define LDS_COMPILER_FENCE() asm volatile("" ::: "memory")

__device__ __forceinline__ int reflect_idx(int t, int n) {
    if (t < 0) t = -t;
    if (t > n - 1) t = 2 * (n - 1) - t;
    return t;
}

// ---------------- K1: H-pass conv (256 thr) + Sobel mask (128 thr) + out zero ----------------
__global__ __launch_bounds__(384)
void prep_kernel(const float* __restrict__ orig,
                 const float* __restrict__ smooth,
                 float* __restrict__ Gh, float* __restrict__ Qh,
                 float* __restrict__ mask, float* __restrict__ out) {
    __shared__ float row[170], rsq[170], wt[KWIN];
    const int bid = blockIdx.x;      // bc*128 + h ; bc = b*3+c
    const int h   = bid & 127;
    const int bc  = bid >> 7;
    const int t   = threadIdx.x;
    if (bid == 0 && t == 0) out[0] = 0.f;
    if (t < KWIN) { int k = t - WS; wt[t] = __expf(-SIGMA_SPACE * (float)(k * k)); }
    const float* src = smooth + bc * HW + h * W;
    if (t < 170) {
        float v = src[reflect_idx(t - WS, W)];
        row[t] = v; rsq[t] = v * v;
    }
    __syncthreads();
    if (t < 256) {
        const int w = t & 127;
        const float* buf = (t < 128) ? row : rsq;
        float acc = 0.f;
#pragma unroll
        for (int y = 0; y < KWIN; ++y) acc = fmaf(wt[y], buf[w + y], acc);
        ((t < 128) ? Gh : Qh)[bid * W + w] = acc;
    } else if (bc == 0 || bc == 3) {
        const int b = bc / 3;
        const int w = t - 256;
        const float* ob = orig   + b * CHW;
        const float* sb = smooth + b * CHW;
        int hm = reflect_idx(h - 1, H), hp = reflect_idx(h + 1, H);
        int wm = reflect_idx(w - 1, W), wp = reflect_idx(w + 1, W);
        float eo = 0.f, es = 0.f;
#pragma unroll
        for (int c = 0; c < C; ++c) {
            const float* po = ob + c * HW;
            const float* ps = sb + c * HW;
            {
                float a00 = po[hm * W + wm], a01 = po[hm * W + w], a02 = po[hm * W + wp];
                float a10 = po[h  * W + wm],                        a12 = po[h  * W + wp];
                float a20 = po[hp * W + wm], a21 = po[hp * W + w], a22 = po[hp * W + wp];
                float gx = (a02 - a00) + 2.f * (a12 - a10) + (a22 - a20);
                float gy = (a20 - a00) + 2.f * (a21 - a01) + (a22 - a02);
                eo += sqrtf(gx * gx + gy * gy);
            }
            {
                float a00 = ps[hm * W + wm], a01 = ps[hm * W + w], a02 = ps[hm * W + wp];
                float a10 = ps[h  * W + wm],                        a12 = ps[h  * W + wp];
                float a20 = ps[hp * W + wm], a21 = ps[hp * W + w], a22 = ps[hp * W + wp];
                float gx = (a02 - a00) + 2.f * (a12 - a10) + (a22 - a20);
                float gy = (a20 - a00) + 2.f * (a21 - a01) + (a22 - a02);
                es += sqrtf(gx * gx + gy * gy);
            }
        }
        float m = ((eo < 20.0f) && ((es - eo) > 10.0f)) ? 1.0f : 0.0f;
        mask[(b << 14) + (h << 7) + w] = m;
    }
}

// ---- K2: barrier-free wave-private screen + fused AL + exact survivor recompute ----
__global__ __launch_bounds__(256)
void screen_kernel(const float* __restrict__ orig,
                   const float* __restrict__ smooth,
                   const float* __restrict__ Gh, const float* __restrict__ Qh,
                   const float* __restrict__ mask,
                   float* __restrict__ out) {
    __shared__ uint2 oA[4 * WSLOTS];    // 4 wave-private slices
    __shared__ float red[4];

    const int t    = threadIdx.x;
    const int wave = t >> 6;
    const int lane = t & 63;
    const int gw   = blockIdx.x * 4 + wave;   // [0, 8192)
    const int split = gw & 15;                // xi-slice
    const int half  = (gw >> 4) & 1;
    const int h     = (gw >> 5) & 127;
    const int b     = gw >> 12;
    const int w0    = half * 64;
    const int w     = w0 + lane;
    const int wb    = wave * WSLOTS;

    const float* ob  = orig   + b * CHW;
    const float* sb  = smooth + b * CHW;
    const float* GhB = Gh + b * 3 * HW;
    const float* QhB = Qh + b * 3 * HW;

    const int pix = (b << 14) + (h << 7) + w;
    const float m = mask[pix];
    const float thr_l = (m == 0.0f) ? SQ_THR_FP16 : -1.0f;

    float o0c, o1c, o2c, s0c, s1c, s2c;
    {
        int hw = h * W + w;
        o0c = ob[hw]; o1c = ob[HW + hw]; o2c = ob[2 * HW + hw];
        s0c = sb[hw]; s1c = sb[HW + hw]; s2c = sb[2 * HW + hw];
    }
    const h2_t c01h = { (_Float16)o0c, (_Float16)o1c };
    const h2_t c2xh = { (_Float16)o2c, (_Float16)0.f };

    // AL constants (separable-Gaussian identity)
    const float n0 = s0c * s0c * SG, n1 = s1c * s1c * SG, n2 = s2c * s2c * SG;
    const float tc0 = -2.f * s0c, tc1 = -2.f * s1c, tc2 = -2.f * s2c;

    // wave's extended-row source columns (reflection pre-applied, xi-invariant)
    const int  sc1  = reflect_idx(w0 - WS + lane, W);           // element lane
    const bool has2 = (lane < 42);
    const int  sc2  = reflect_idx(w0 + 43 + lane, W);           // element 64+lane

    float accAL = 0.f, accS = 0.f;

    // ---- prologue: prefetch staging for first xi ----
    float a0, a1, a2, b0 = 0.f, b1 = 0.f, b2 = 0.f;
    {
        const int rr0 = reflect_idx(h + split - WS, H);
        const float* prow = ob + rr0 * W;
        a0 = prow[sc1]; a1 = prow[HW + sc1]; a2 = prow[2 * HW + sc1];
        if (has2) { b0 = prow[sc2]; b1 = prow[HW + sc2]; b2 = prow[2 * HW + sc2]; }
    }

    for (int xi = split; xi < KWIN; xi += NSPLIT) {
        const int x  = xi - WS;
        const int rr = reflect_idx(h + x, H);        // wave-uniform source row

        // (fence) previous iteration's LDS reads must complete (compiler-order) first
        LDS_COMPILER_FENCE();
        // write this xi's staged row (regs loaded last iter / prologue)
        {
            h2_t v01 = { (_Float16)a0, (_Float16)a1 };
            h2_t v2x = { (_Float16)a2, (_Float16)0.f };
            oA[wb + lane] = make_uint2(__builtin_bit_cast(unsigned, v01),
                                       __builtin_bit_cast(unsigned, v2x));
            if (has2) {
                h2_t u01 = { (_Float16)b0, (_Float16)b1 };
                h2_t u2x = { (_Float16)b2, (_Float16)0.f };
                oA[wb + 64 + lane] = make_uint2(__builtin_bit_cast(unsigned, u01),
                                                __builtin_bit_cast(unsigned, u2x));
            }
        }
        // (fence) screen reads below must not hoist above the writes
        LDS_COMPILER_FENCE();

        // prefetch next xi's staged row (overlaps with screen; no barrier in the way)
        const int xin = xi + NSPLIT;
        if (xin < KWIN) {
            const int rrn = reflect_idx(h + xin - WS, H);
            const float* prow = ob + rrn * W;
            a0 = prow[sc1]; a1 = prow[HW + sc1]; a2 = prow[2 * HW + sc1];
            if (has2) { b0 = prow[sc2]; b1 = prow[HW + sc2]; b2 = prow[2 * HW + sc2]; }
        }

        // fused AL term for this pixel at this xi
        {
            const int ga = rr * W + w;
            float G0 = GhB[ga], G1 = GhB[HW + ga], G2 = GhB[2 * HW + ga];
            float Q0 = QhB[ga], Q1 = QhB[HW + ga], Q2 = QhB[2 * HW + ga];
            float xf = (float)x;
            float wtx = __expf(-SIGMA_SPACE * xf * xf);
            float gsum = (n0 + fmaf(tc0, G0, Q0))
                       + (n1 + fmaf(tc1, G1, Q1))
                       + (n2 + fmaf(tc2, G2, Q2));
            accAL = fmaf(wtx, gsum, accAL);
        }

        // ---- branchless fp16 screen over 43 yi (wave-private LDS, no sync) ----
        unsigned mA = 0u, mB_ = 0u;
#pragma unroll
        for (int yi = 0; yi < KWIN; ++yi) {
            uint2 vv = oA[wb + lane + yi];
            h2_t p01 = __builtin_bit_cast(h2_t, vv.x);
            h2_t p2x = __builtin_bit_cast(h2_t, vv.y);
            h2_t d01 = c01h - p01;
            h2_t d2x = c2xh - p2x;
            float sq = __builtin_amdgcn_fdot2(d01, d01,
                        __builtin_amdgcn_fdot2(d2x, d2x, 0.f, false), false);
            unsigned bit = (sq < thr_l) ? 1u : 0u;
            if (yi < 21) mA  = (mA  << 1) | bit;   // bit (20-yi)
            else         mB_ = (mB_ << 1) | bit;   // bit (42-yi)
        }
        if (xi == WS) mB_ &= ~(1u << 21);          // self-pair term is exactly 0

        // ---- immediate consumption: exact fp32 recompute from global (L2-resident) ----
        while (mA | mB_) {
            int yi;
            if (mA) { int p = __builtin_ctz(mA); mA &= mA - 1; yi = 20 - p; }
            else    { int p = __builtin_ctz(mB_); mB_ &= mB_ - 1; yi = 42 - p; }
            int ww = reflect_idx(w + yi - WS, W);
            int a = rr * W + ww;
            float on0 = ob[a], on1 = ob[HW + a], on2 = ob[2 * HW + a];
            float sn0 = sb[a], sn1 = sb[HW + a], sn2 = sb[2 * HW + a];
            float g0 = o0c - on0, g1 = o1c - on1, g2 = o2c - on2;
            float sq = fmaf(g0, g0, fmaf(g1, g1, g2 * g2));
            float tt = -NEG_SC_LOG2E * sq;
            float d0 = fabsf(s0c - sn0), d1 = fabsf(s1c - sn1), d2 = fabsf(s2c - sn2);
            accS += __builtin_amdgcn_exp2f(fmaf(0.8f, __builtin_amdgcn_logf(d0), tt))
                  + __builtin_amdgcn_exp2f(fmaf(0.8f, __builtin_amdgcn_logf(d1), tt))
                  + __builtin_amdgcn_exp2f(fmaf(0.8f, __builtin_amdgcn_logf(d2), tt));
        }
        // (fence) next iteration's LDS writes must not hoist above this screen
        LDS_COMPILER_FENCE();
    }

    float r = m * accAL + accS;
#pragma unroll
    for (int off = 32; off > 0; off >>= 1) r += __shfl_down(r, off, 64);
    if (lane == 0) red[wave] = r;
    __syncthreads();                               // only barrier in the kernel
    if (t == 0) atomicAdd(out, (red[0] + red[1] + red[2] + red[3]) * (1.0f / (float)NPIX));
}

extern "C" void kernel_launch(void* const* d_in, const int* in_sizes, int n_in,
                              void* d_out, int out_size, void* d_ws, size_t ws_size,
                              hipStream_t stream) {
    const float* orig   = (const float*)d_in[0];
    const float* smooth = (const float*)d_in[1];
    float* out = (float*)d_out;

    float* Gh  = (float*)d_ws;                   // 98304 floats
    float* Qh  = Gh + B * C * HW;                // 98304 floats
    float* msk = Qh + B * C * HW;                // 32768 floats

    prep_kernel<<<B * C * H, 384, 0, stream>>>(orig, smooth, Gh, Qh, msk, out);
    // 8192 waves = B * H * 2 halves * NSPLIT(16) ; 4 waves/block -> 2048 blocks
    screen_kernel<<<(B * H * 2 * NSPLIT) / 4, 256, 0, stream>>>(orig, smooth, Gh, Qh, msk, out);
}

// Round 14
// 85.245 us; speedup vs baseline: 1.0753x; 1.0753x over previous
//
#include <hip/hip_runtime.h>
#include <math.h>

#define WS 21
#define KWIN 43            // 2*WS+1
#define H 128
#define W 128
#define B 2
#define C 3
#define HW (H * W)
#define CHW (C * H * W)
#define NPIX (B * H * W)   // 32768
#define SIGMA_SPACE (1.0f / 98.0f)
#define NSPLIT 8           // r11-validated best (4096 waves); r13's 16 regressed
#define SQ_THR_FP16 0.17f  // fp16-screen threshold (validated r7-r13, absmax ~0)
#define NEG_SC_LOG2E 72.1347520445f   // 50*log2(e)
#define SG 17.509290f      // sum_{k=-21..21} exp(-k^2/98)
#define WSLOTS 108         // wave-private LDS slice (106 used, uint2 units)

typedef _Float16 h2_t __attribute__((ext_vector_type(2)));

// Compiler-only fence: wave-private LDS relies on HW per-wave DS ordering; this
// stops compiler reordering of lane-local LDS ops whose cross-lane aliasing it
// cannot see (r10 bug -> r11 fix, validated absmax 1.0 -> 0.0).
#define LDS_COMPILER_FENCE() asm volatile("" ::: "memory")

__device__ __forceinline__ int reflect_idx(int t, int n) {
    if (t < 0) t = -t;
    if (t > n - 1) t = 2 * (n - 1) - t;
    return t;
}

// ---------------- K1: H-pass conv (256 thr) + Sobel mask (128 thr) + out zero ----------------
__global__ __launch_bounds__(384)
void prep_kernel(const float* __restrict__ orig,
                 const float* __restrict__ smooth,
                 float* __restrict__ Gh, float* __restrict__ Qh,
                 float* __restrict__ mask, float* __restrict__ out) {
    __shared__ float row[170], rsq[170], wt[KWIN];
    const int bid = blockIdx.x;      // bc*128 + h ; bc = b*3+c
    const int h   = bid & 127;
    const int bc  = bid >> 7;
    const int t   = threadIdx.x;
    if (bid == 0 && t == 0) out[0] = 0.f;
    if (t < KWIN) { int k = t - WS; wt[t] = __expf(-SIGMA_SPACE * (float)(k * k)); }
    const float* src = smooth + bc * HW + h * W;
    if (t < 170) {
        float v = src[reflect_idx(t - WS, W)];
        row[t] = v; rsq[t] = v * v;
    }
    __syncthreads();
    if (t < 256) {
        const int w = t & 127;
        const float* buf = (t < 128) ? row : rsq;
        float acc = 0.f;
#pragma unroll
        for (int y = 0; y < KWIN; ++y) acc = fmaf(wt[y], buf[w + y], acc);
        ((t < 128) ? Gh : Qh)[bid * W + w] = acc;
    } else if (bc == 0 || bc == 3) {
        const int b = bc / 3;
        const int w = t - 256;
        const float* ob = orig   + b * CHW;
        const float* sb = smooth + b * CHW;
        int hm = reflect_idx(h - 1, H), hp = reflect_idx(h + 1, H);
        int wm = reflect_idx(w - 1, W), wp = reflect_idx(w + 1, W);
        float eo = 0.f, es = 0.f;
#pragma unroll
        for (int c = 0; c < C; ++c) {
            const float* po = ob + c * HW;
            const float* ps = sb + c * HW;
            {
                float a00 = po[hm * W + wm], a01 = po[hm * W + w], a02 = po[hm * W + wp];
                float a10 = po[h  * W + wm],                        a12 = po[h  * W + wp];
                float a20 = po[hp * W + wm], a21 = po[hp * W + w], a22 = po[hp * W + wp];
                float gx = (a02 - a00) + 2.f * (a12 - a10) + (a22 - a20);
                float gy = (a20 - a00) + 2.f * (a21 - a01) + (a22 - a02);
                eo += sqrtf(gx * gx + gy * gy);
            }
            {
                float a00 = ps[hm * W + wm], a01 = ps[hm * W + w], a02 = ps[hm * W + wp];
                float a10 = ps[h  * W + wm],                        a12 = ps[h  * W + wp];
                float a20 = ps[hp * W + wm], a21 = ps[hp * W + w], a22 = ps[hp * W + wp];
                float gx = (a02 - a00) + 2.f * (a12 - a10) + (a22 - a20);
                float gy = (a20 - a00) + 2.f * (a21 - a01) + (a22 - a02);
                es += sqrtf(gx * gx + gy * gy);
            }
        }
        float m = ((eo < 20.0f) && ((es - eo) > 10.0f)) ? 1.0f : 0.0f;
        mask[(b << 14) + (h << 7) + w] = m;
    }
}

// ---- K2: barrier-free wave-private screen + fused AL (prefetched) + exact survivors ----
__global__ __launch_bounds__(256)
void screen_kernel(const float* __restrict__ orig,
                   const float* __restrict__ smooth,
                   const float* __restrict__ Gh, const float* __restrict__ Qh,
                   const float* __restrict__ mask,
                   float* __restrict__ out) {
    __shared__ uint2 oA[4 * WSLOTS];    // 4 wave-private slices
    __shared__ float red[4];

    const int t    = threadIdx.x;
    const int wave = t >> 6;
    const int lane = t & 63;
    const int gw   = blockIdx.x * 4 + wave;   // [0, 4096)
    const int split = gw & 7;                 // xi-slice
    const int half  = (gw >> 3) & 1;
    const int h     = (gw >> 4) & 127;
    const int b     = gw >> 11;
    const int w0    = half * 64;
    const int w     = w0 + lane;
    const int wb    = wave * WSLOTS;

    const float* ob  = orig   + b * CHW;
    const float* sb  = smooth + b * CHW;
    const float* GhB = Gh + b * 3 * HW;
    const float* QhB = Qh + b * 3 * HW;

    const int pix = (b << 14) + (h << 7) + w;
    const float m = mask[pix];
    const float thr_l = (m == 0.0f) ? SQ_THR_FP16 : -1.0f;

    float o0c, o1c, o2c, s0c, s1c, s2c;
    {
        int hw = h * W + w;
        o0c = ob[hw]; o1c = ob[HW + hw]; o2c = ob[2 * HW + hw];
        s0c = sb[hw]; s1c = sb[HW + hw]; s2c = sb[2 * HW + hw];
    }
    const h2_t c01h = { (_Float16)o0c, (_Float16)o1c };
    const h2_t c2xh = { (_Float16)o2c, (_Float16)0.f };

    // AL constants (separable-Gaussian identity)
    const float n0 = s0c * s0c * SG, n1 = s1c * s1c * SG, n2 = s2c * s2c * SG;
    const float tc0 = -2.f * s0c, tc1 = -2.f * s1c, tc2 = -2.f * s2c;

    // wave's extended-row source columns (reflection pre-applied, xi-invariant)
    const int  sc1  = reflect_idx(w0 - WS + lane, W);           // element lane
    const bool has2 = (lane < 42);
    const int  sc2  = reflect_idx(w0 + 43 + lane, W);           // element 64+lane

    float accAL = 0.f, accS = 0.f;

    // ---- prologue: prefetch staging AND AL loads for first xi ----
    float a0, a1, a2, b0 = 0.f, b1 = 0.f, b2 = 0.f;
    float G0, G1, G2, Q0, Q1, Q2;
    {
        const int rr0 = reflect_idx(h + split - WS, H);
        const float* prow = ob + rr0 * W;
        a0 = prow[sc1]; a1 = prow[HW + sc1]; a2 = prow[2 * HW + sc1];
        if (has2) { b0 = prow[sc2]; b1 = prow[HW + sc2]; b2 = prow[2 * HW + sc2]; }
        const int ga = rr0 * W + w;
        G0 = GhB[ga]; G1 = GhB[HW + ga]; G2 = GhB[2 * HW + ga];
        Q0 = QhB[ga]; Q1 = QhB[HW + ga]; Q2 = QhB[2 * HW + ga];
    }

    for (int xi = split; xi < KWIN; xi += NSPLIT) {
        const int x  = xi - WS;
        const int rr = reflect_idx(h + x, H);        // wave-uniform source row

        // (fence) previous iteration's LDS reads must complete (compiler-order) first
        LDS_COMPILER_FENCE();
        // write this xi's staged row (regs loaded last iter / prologue)
        {
            h2_t v01 = { (_Float16)a0, (_Float16)a1 };
            h2_t v2x = { (_Float16)a2, (_Float16)0.f };
            oA[wb + lane] = make_uint2(__builtin_bit_cast(unsigned, v01),
                                       __builtin_bit_cast(unsigned, v2x));
            if (has2) {
                h2_t u01 = { (_Float16)b0, (_Float16)b1 };
                h2_t u2x = { (_Float16)b2, (_Float16)0.f };
                oA[wb + 64 + lane] = make_uint2(__builtin_bit_cast(unsigned, u01),
                                                __builtin_bit_cast(unsigned, u2x));
            }
        }
        // (fence) screen reads below must not hoist above the writes
        LDS_COMPILER_FENCE();

        // fused AL term for this pixel at this xi (G/Q prefetched last iteration)
        {
            float xf = (float)x;
            float wtx = __expf(-SIGMA_SPACE * xf * xf);
            float gsum = (n0 + fmaf(tc0, G0, Q0))
                       + (n1 + fmaf(tc1, G1, Q1))
                       + (n2 + fmaf(tc2, G2, Q2));
            accAL = fmaf(wtx, gsum, accAL);
        }

        // prefetch next xi's staged row + AL loads (overlaps with screen; no barrier)
        const int xin = xi + NSPLIT;
        if (xin < KWIN) {
            const int rrn = reflect_idx(h + xin - WS, H);
            const float* prow = ob + rrn * W;
            a0 = prow[sc1]; a1 = prow[HW + sc1]; a2 = prow[2 * HW + sc1];
            if (has2) { b0 = prow[sc2]; b1 = prow[HW + sc2]; b2 = prow[2 * HW + sc2]; }
            const int gan = rrn * W + w;
            G0 = GhB[gan]; G1 = GhB[HW + gan]; G2 = GhB[2 * HW + gan];
            Q0 = QhB[gan]; Q1 = QhB[HW + gan]; Q2 = QhB[2 * HW + gan];
        }

        // ---- branchless fp16 screen over 43 yi (wave-private LDS, no sync) ----
        unsigned mA = 0u, mB_ = 0u;
#pragma unroll
        for (int yi = 0; yi < KWIN; ++yi) {
            uint2 vv = oA[wb + lane + yi];
            h2_t p01 = __builtin_bit_cast(h2_t, vv.x);
            h2_t p2x = __builtin_bit_cast(h2_t, vv.y);
            h2_t d01 = c01h - p01;
            h2_t d2x = c2xh - p2x;
            float sq = __builtin_amdgcn_fdot2(d01, d01,
                        __builtin_amdgcn_fdot2(d2x, d2x, 0.f, false), false);
            unsigned bit = (sq < thr_l) ? 1u : 0u;
            if (yi < 21) mA  = (mA  << 1) | bit;   // bit (20-yi)
            else         mB_ = (mB_ << 1) | bit;   // bit (42-yi)
        }
        if (xi == WS) mB_ &= ~(1u << 21);          // self-pair term is exactly 0

        // ---- immediate consumption: exact fp32 recompute from global (L2-resident) ----
        while (mA | mB_) {
            int yi;
            if (mA) { int p = __builtin_ctz(mA); mA &= mA - 1; yi = 20 - p; }
            else    { int p = __builtin_ctz(mB_); mB_ &= mB_ - 1; yi = 42 - p; }
            int ww = reflect_idx(w + yi - WS, W);
            int a = rr * W + ww;
            float on0 = ob[a], on1 = ob[HW + a], on2 = ob[2 * HW + a];
            float sn0 = sb[a], sn1 = sb[HW + a], sn2 = sb[2 * HW + a];
            float g0 = o0c - on0, g1 = o1c - on1, g2 = o2c - on2;
            float sq = fmaf(g0, g0, fmaf(g1, g1, g2 * g2));
            float tt = -NEG_SC_LOG2E * sq;
            float d0 = fabsf(s0c - sn0), d1 = fabsf(s1c - sn1), d2 = fabsf(s2c - sn2);
            accS += __builtin_amdgcn_exp2f(fmaf(0.8f, __builtin_amdgcn_logf(d0), tt))
                  + __builtin_amdgcn_exp2f(fmaf(0.8f, __builtin_amdgcn_logf(d1), tt))
                  + __builtin_amdgcn_exp2f(fmaf(0.8f, __builtin_amdgcn_logf(d2), tt));
        }
        // (fence) next iteration's LDS writes must not hoist above this screen
        LDS_COMPILER_FENCE();
    }

    float r = m * accAL + accS;
#pragma unroll
    for (int off = 32; off > 0; off >>= 1) r += __shfl_down(r, off, 64);
    if (lane == 0) red[wave] = r;
    __syncthreads();                               // only barrier in the kernel
    if (t == 0) atomicAdd(out, (red[0] + red[1] + red[2] + red[3]) * (1.0f / (float)NPIX));
}

extern "C" void kernel_launch(void* const* d_in, const int* in_sizes, int n_in,
                              void* d_out, int out_size, void* d_ws, size_t ws_size,
                              hipStream_t stream) {
    const float* orig   = (const float*)d_in[0];
    const float* smooth = (const float*)d_in[1];
    float* out = (float*)d_out;

    float* Gh  = (float*)d_ws;                   // 98304 floats
    float* Qh  = Gh + B * C * HW;                // 98304 floats
    float* msk = Qh + B * C * HW;                // 32768 floats

    prep_kernel<<<B * C * H, 384, 0, stream>>>(orig, smooth, Gh, Qh, msk, out);
    // 4096 waves = B * H * 2 halves * NSPLIT(8) ; 4 waves/block -> 1024 blocks
    screen_kernel<<<(B * H * 2 * NSPLIT) / 4, 256, 0, stream>>>(orig, smooth, Gh, Qh, msk, out);
}